// Round 5
// baseline (461.385 us; speedup 1.0000x reference)
//
#include <hip/hip_runtime.h>

// Integrate-and-fire, TBN layout. One thread per 4 consecutive neurons.
// R5: four rounds of source-level pipelining all produced VGPR=32 / ~1 load
// in flight per wave -> 5.5us per congested load-wait, 3 TB/s ceiling by
// Little's law. Fix: raw inline-asm global_load_dwordx4 pipeline the
// compiler cannot sink or serialize. Issue 24 loads, vmcnt(8); consume
// t0..15 (bitmasks, NO stores -> vmem queue stays loads-only); issue 8,
// vmcnt(8); consume t16..23; vmcnt(0); consume t24..31; then a wait-free
// nt-store epilogue. 24 KiB in flight/wave, ~384 KiB/CU outstanding.

typedef float v4f __attribute__((ext_vector_type(4)));

#define T_STEPS 32

// one IF step on 4 lanes-worth of state, accumulating spike bits
#define IF_STEP(xv, t)                                \
    do {                                              \
        float a0 = v0 + (xv).x;                       \
        float a1 = v1 + (xv).y;                       \
        float a2 = v2 + (xv).z;                       \
        float a3 = v3 + (xv).w;                       \
        bool s0 = a0 >= 1.0f;                         \
        bool s1 = a1 >= 1.0f;                         \
        bool s2 = a2 >= 1.0f;                         \
        bool s3 = a3 >= 1.0f;                         \
        m0 |= (unsigned)s0 << (t);                    \
        m1 |= (unsigned)s1 << (t);                    \
        m2 |= (unsigned)s2 << (t);                    \
        m3 |= (unsigned)s3 << (t);                    \
        v0 = s0 ? a0 - 1.0f : a0;                     \
        v1 = s1 ? a1 - 1.0f : a1;                     \
        v2 = s2 ? a2 - 1.0f : a2;                     \
        v3 = s3 ? a3 - 1.0f : a3;                     \
    } while (0)

#define LD(i) "global_load_dwordx4 %" #i ", %24, %26\n\t" \
              "v_add_u32 %24, %25, %24\n\t"

#define LD2(i) "global_load_dwordx4 %" #i ", %16, %18\n\t" \
               "v_add_u32 %16, %17, %16\n\t"

__global__ __launch_bounds__(256) void if_kernel(const float* __restrict__ x,
                                                 float* __restrict__ y,
                                                 int bn4) {
    int idx = blockIdx.x * blockDim.x + threadIdx.x;
    if (idx >= bn4) return;

    unsigned voff = (unsigned)idx * 16u;    // byte offset of this thread's float4
    unsigned stride = (unsigned)bn4 * 16u;  // plane stride in bytes (8 MiB)

    v4f d0, d1, d2, d3, d4, d5, d6, d7, d8, d9, d10, d11,
        d12, d13, d14, d15, d16, d17, d18, d19, d20, d21, d22, d23;
    v4f e0, e1, e2, e3, e4, e5, e6, e7;

    // ---- block 1: issue loads t=0..23, wait until the oldest 16 retire ----
    asm volatile(
        LD(0) LD(1) LD(2) LD(3) LD(4) LD(5) LD(6) LD(7)
        LD(8) LD(9) LD(10) LD(11) LD(12) LD(13) LD(14) LD(15)
        LD(16) LD(17) LD(18) LD(19) LD(20) LD(21) LD(22) LD(23)
        "s_waitcnt vmcnt(8)\n\t"
        : "=v"(d0), "=v"(d1), "=v"(d2), "=v"(d3), "=v"(d4), "=v"(d5),
          "=v"(d6), "=v"(d7), "=v"(d8), "=v"(d9), "=v"(d10), "=v"(d11),
          "=v"(d12), "=v"(d13), "=v"(d14), "=v"(d15), "=v"(d16), "=v"(d17),
          "=v"(d18), "=v"(d19), "=v"(d20), "=v"(d21), "=v"(d22), "=v"(d23),
          "+v"(voff)
        : "s"(stride), "s"(x));

    float v0 = 0.f, v1 = 0.f, v2 = 0.f, v3 = 0.f;
    unsigned m0 = 0u, m1 = 0u, m2 = 0u, m3 = 0u;

    // consume t=0..15 (register math only — no vmem enters the queue)
    IF_STEP(d0, 0);  IF_STEP(d1, 1);  IF_STEP(d2, 2);  IF_STEP(d3, 3);
    IF_STEP(d4, 4);  IF_STEP(d5, 5);  IF_STEP(d6, 6);  IF_STEP(d7, 7);
    IF_STEP(d8, 8);  IF_STEP(d9, 9);  IF_STEP(d10, 10); IF_STEP(d11, 11);
    IF_STEP(d12, 12); IF_STEP(d13, 13); IF_STEP(d14, 14); IF_STEP(d15, 15);

    // ---- block 2: issue loads t=24..31; wait until t16..23 (oldest) retire.
    // d16..d23 are threaded through as "+v" so their uses can't hoist above
    // this wait.
    asm volatile(
        LD2(0) LD2(1) LD2(2) LD2(3) LD2(4) LD2(5) LD2(6) LD2(7)
        "s_waitcnt vmcnt(8)\n\t"
        : "=v"(e0), "=v"(e1), "=v"(e2), "=v"(e3),
          "=v"(e4), "=v"(e5), "=v"(e6), "=v"(e7),
          "+v"(d16), "+v"(d17), "+v"(d18), "+v"(d19),
          "+v"(d20), "+v"(d21), "+v"(d22), "+v"(d23),
          "+v"(voff)
        : "s"(stride), "s"(x));

    IF_STEP(d16, 16); IF_STEP(d17, 17); IF_STEP(d18, 18); IF_STEP(d19, 19);
    IF_STEP(d20, 20); IF_STEP(d21, 21); IF_STEP(d22, 22); IF_STEP(d23, 23);

    // ---- block 3: drain the last 8 loads ----
    asm volatile(
        "s_waitcnt vmcnt(0)\n\t"
        : "+v"(e0), "+v"(e1), "+v"(e2), "+v"(e3),
          "+v"(e4), "+v"(e5), "+v"(e6), "+v"(e7));

    IF_STEP(e0, 24); IF_STEP(e1, 25); IF_STEP(e2, 26); IF_STEP(e3, 27);
    IF_STEP(e4, 28); IF_STEP(e5, 29); IF_STEP(e6, 30); IF_STEP(e7, 31);

    // ---- epilogue: expand bitmasks, 32 wait-free nt stores ----
    v4f* yp = (v4f*)y + idx;
#pragma unroll
    for (int t = 0; t < T_STEPS; ++t) {
        v4f out;
        out.x = ((m0 >> t) & 1u) ? 1.0f : 0.0f;
        out.y = ((m1 >> t) & 1u) ? 1.0f : 0.0f;
        out.z = ((m2 >> t) & 1u) ? 1.0f : 0.0f;
        out.w = ((m3 >> t) & 1u) ? 1.0f : 0.0f;
        __builtin_nontemporal_store(out, yp + (size_t)t * bn4);
    }
}

extern "C" void kernel_launch(void* const* d_in, const int* in_sizes, int n_in,
                              void* d_out, int out_size, void* d_ws, size_t ws_size,
                              hipStream_t stream) {
    const float* x = (const float*)d_in[0];
    float* y = (float*)d_out;

    int total = in_sizes[0];        // T*B*N = 67,108,864
    int bn = total / T_STEPS;       // B*N  =  2,097,152
    int bn4 = bn / 4;               //        524,288 float4 columns

    int block = 256;
    int grid = (bn4 + block - 1) / block;  // 2048 blocks

    if_kernel<<<grid, block, 0, stream>>>(x, y, bn4);
}